// Round 6
// baseline (293.752 us; speedup 1.0000x reference)
//
#include <hip/hip_runtime.h>

#define N_   512
#define V_   3889
#define V3   11667      // V_*3
#define J_   35
#define NB_  20
#define PF_K 306        // 34*9
#define KP   320        // K padded to 10 MFMA k-steps of 32
#define KSTEPS 10
#define EP   11776      // 46*256, e padded

typedef __attribute__((ext_vector_type(8))) short short8;
typedef __attribute__((ext_vector_type(4))) float f32x4;

__constant__ int c_parents[J_] = {0,0,1,2,3,4,5,6,7,8,9,6,11,12,13,6,15,16,17,18,
                                  16,20,21,22,23,16,25,26,27,28,29,30,16,1,1};

static __device__ __forceinline__ unsigned short f2bf(float x) {
  union { float f; unsigned int u; } v; v.f = x;
  unsigned int r = v.u + 0x7FFF + ((v.u >> 16) & 1);   // round-to-nearest-even
  return (unsigned short)(r >> 16);
}

// ===== prep (one dispatch, grid-partitioned): =================================
//  part A: v_shaped = v_template + deform + beta @ shapedirs
//  part B: JrT36[j][v] = Jr[v][j] (row 35 = 0)
//  part C: wtsT[j][v]  = wts[v][j]
//  part D: pdT[e][k] bf16 transpose+pack of posedirs
#define VS_G 4
#define PREP_VS  (46 * (N_ / VS_G))               // 5888
#define PREP_JRT ((36 * V_ + 255) / 256)          // 547
#define PREP_WTS ((J_ * V_ + 255) / 256)          // 532
#define PREP_PD  (EP / 64)                        // 184
#define PREP_BLOCKS (PREP_VS + PREP_JRT + PREP_WTS + PREP_PD)
__global__ __launch_bounds__(256) void k_prep_all(
    const float* __restrict__ beta, const float* __restrict__ deform,
    const float* __restrict__ vt,   const float* __restrict__ sd,
    const float* __restrict__ Jr,   const float* __restrict__ wts,
    const float* __restrict__ pd,
    float* __restrict__ VS, float* __restrict__ JrT36,
    float* __restrict__ wtsT, unsigned short* __restrict__ pdT) {
  int b = blockIdx.x;
  int t = threadIdx.x;
  if (b < PREP_VS) {                       // ---- v_shaped ----
    int e  = (b % 46) * 256 + t;
    int n0 = (b / 46) * VS_G;
    if (e >= V3) return;
    float base = vt[e];
    float acc[VS_G];
#pragma unroll
    for (int i = 0; i < VS_G; ++i) acc[i] = base + deform[(size_t)(n0 + i) * V3 + e];
#pragma unroll
    for (int bb = 0; bb < NB_; ++bb) {
      float sv = sd[(size_t)bb * V3 + e];
#pragma unroll
      for (int i = 0; i < VS_G; ++i) acc[i] += beta[(n0 + i) * NB_ + bb] * sv;
    }
#pragma unroll
    for (int i = 0; i < VS_G; ++i) VS[(size_t)(n0 + i) * V3 + e] = acc[i];
  } else if (b < PREP_VS + PREP_JRT) {     // ---- JrT36 ----
    int idx = (b - PREP_VS) * 256 + t;
    if (idx >= 36 * V_) return;
    int j = idx / V_, v = idx % V_;
    JrT36[idx] = (j < J_) ? Jr[v * J_ + j] : 0.f;
  } else if (b < PREP_VS + PREP_JRT + PREP_WTS) {   // ---- wtsT ----
    int idx = (b - PREP_VS - PREP_JRT) * 256 + t;
    if (idx >= J_ * V_) return;
    int j = idx / V_, v = idx % V_;
    wtsT[idx] = wts[v * J_ + j];
  } else {                                 // ---- pdT bf16 ----
    int bb = b - PREP_VS - PREP_JRT - PREP_WTS;
    int e  = bb * 64 + (t & 63);
    int kg = t >> 6;                        // 0..3 -> k range [kg*80, +80)
    bool ev = e < V3;
    for (int kk = 0; kk < 80; kk += 8) {
      int k0 = kg * 80 + kk;
      union { unsigned short u[8]; short8 s; } pk;
#pragma unroll
      for (int ii = 0; ii < 8; ++ii) {
        int k = k0 + ii;
        float x = (ev && k < PF_K) ? pd[(size_t)k * V3 + e] : 0.f;
        pk.u[ii] = f2bf(x);
      }
      *(short8*)(pdT + (size_t)e * KP + k0) = pk.s;
    }
  }
}

// ===== dst[n,j,c] = sum_v src[n,v,c] * JrT36[j,v]  (j-groups of 9) ===========
#define JR4_JG 9
#define JR4_GROUPS 4
__global__ __launch_bounds__(256) void k_jreduce4(
    const float* __restrict__ src, const float* __restrict__ JrT36,
    float* __restrict__ dst) {
  int t = threadIdx.x;
  int lane = t & 63;
  int w = blockIdx.x * 4 + (t >> 6);
  int n  = w >> 2;
  int j0 = (w & 3) * JR4_JG;
  const float* s0 = src + (size_t)n * V3;

  float acc[JR4_JG][3];
#pragma unroll
  for (int jj = 0; jj < JR4_JG; ++jj)
#pragma unroll
    for (int cc = 0; cc < 3; ++cc) acc[jj][cc] = 0.f;

#pragma unroll 2
  for (int iv = 0; iv < (V_ + 63) / 64; ++iv) {
    int v = iv * 64 + lane;
    bool ok = v < V_;
    float jr[JR4_JG];
#pragma unroll
    for (int jj = 0; jj < JR4_JG; ++jj)
      jr[jj] = ok ? JrT36[(size_t)(j0 + jj) * V_ + v] : 0.f;
    float sx = ok ? s0[3 * v + 0] : 0.f;
    float sy = ok ? s0[3 * v + 1] : 0.f;
    float sz = ok ? s0[3 * v + 2] : 0.f;
#pragma unroll
    for (int jj = 0; jj < JR4_JG; ++jj) {
      acc[jj][0] += jr[jj] * sx;
      acc[jj][1] += jr[jj] * sy;
      acc[jj][2] += jr[jj] * sz;
    }
  }

#pragma unroll
  for (int jj = 0; jj < JR4_JG; ++jj)
#pragma unroll
    for (int cc = 0; cc < 3; ++cc) {
      float v = acc[jj][cc];
#pragma unroll
      for (int off = 32; off > 0; off >>= 1)
        v += __shfl_down(v, off, 64);
      acc[jj][cc] = v;
    }

  if (lane == 0) {
#pragma unroll
    for (int jj = 0; jj < JR4_JG; ++jj) {
      int j = j0 + jj;
      if (j < J_)
#pragma unroll
        for (int cc = 0; cc < 3; ++cc)
          dst[n * 105 + j * 3 + cc] = acc[jj][cc];
    }
  }
}

// ===== Rodrigues + kinematic chain -> Rs, pfA(bf16 A-frag), A[n][j][3][4] ===
// pfA layout: [mt=n>>4][ks=k>>5][q=(k>>3)&3][m=n&15][o=k&7]
__global__ __launch_bounds__(256) void k_chain_rod(
    const float* __restrict__ theta, const float* __restrict__ Jp,
    const float* __restrict__ se,
    float* __restrict__ Rs_out, unsigned short* __restrict__ pfA,
    float* __restrict__ Aout) {
  __shared__ float loc[4][J_][12];
  __shared__ float res[4][J_][12];
  int t = threadIdx.x;
  int w = t >> 6, l = t & 63;
  int n = blockIdx.x * 4 + w;

  if (l < J_) {
    int j = l;
    const float* th = theta + n * (J_ * 3) + j * 3;
    float t0 = th[0], t1 = th[1], t2 = th[2];
    float angle = sqrtf(t0 * t0 + t1 * t1 + t2 * t2 + 1e-8f);
    float inv = 1.0f / angle;
    float r0 = t0 * inv, r1 = t1 * inv, r2 = t2 * inv;
    float s, c;
    sincosf(angle, &s, &c);
    float omc = 1.0f - c;
    float r[9];
    r[0] = c + omc * r0 * r0;      r[1] = omc * r0 * r1 - s * r2;  r[2] = omc * r0 * r2 + s * r1;
    r[3] = omc * r1 * r0 + s * r2; r[4] = c + omc * r1 * r1;       r[5] = omc * r1 * r2 - s * r0;
    r[6] = omc * r2 * r0 - s * r1; r[7] = omc * r2 * r1 + s * r0;  r[8] = c + omc * r2 * r2;

    float* ro = Rs_out + (size_t)n * (J_ * 9) + j * 9;
#pragma unroll
    for (int k = 0; k < 9; ++k) ro[k] = r[k];
    if (j > 0) {
      int mt = n >> 4, m = n & 15;
#pragma unroll
      for (int kk = 0; kk < 9; ++kk) {
        int k = (j - 1) * 9 + kk;
        float v = r[kk] - ((kk == 0 || kk == 4 || kk == 8) ? 1.0f : 0.0f);
        size_t idx = ((((size_t)mt * KSTEPS + (k >> 5)) * 4 + ((k >> 3) & 3)) * 16 + m) * 8 + (k & 7);
        pfA[idx] = f2bf(v);
      }
    }

    if (j == 0) {
#pragma unroll
      for (int rr = 0; rr < 3; ++rr) {
        loc[w][0][rr * 4 + 0] = r[rr * 3 + 0];
        loc[w][0][rr * 4 + 1] = r[rr * 3 + 1];
        loc[w][0][rr * 4 + 2] = r[rr * 3 + 2];
        loc[w][0][rr * 4 + 3] = Jp[n * 105 + rr];
      }
#pragma unroll
      for (int k = 0; k < 12; ++k) res[w][0][k] = loc[w][0][k];
    } else {
      int p = c_parents[j];
      float si[3], sp[3], jh[3];
#pragma unroll
      for (int cidx = 0; cidx < 3; ++cidx) {
        si[cidx] = se[n * 105 + j * 3 + cidx];
        sp[cidx] = se[n * 105 + p * 3 + cidx];
        jh[cidx] = Jp[n * 105 + j * 3 + cidx] - Jp[n * 105 + p * 3 + cidx];
      }
#pragma unroll
      for (int rr = 0; rr < 3; ++rr) {
        float invp = 1.0f / sp[rr];
        loc[w][j][rr * 4 + 0] = r[rr * 3 + 0] * si[0] * invp;
        loc[w][j][rr * 4 + 1] = r[rr * 3 + 1] * si[1] * invp;
        loc[w][j][rr * 4 + 2] = r[rr * 3 + 2] * si[2] * invp;
        loc[w][j][rr * 4 + 3] = jh[rr];
      }
    }
  } else if (l == 40) {
    // zero the pfA k-pad (k = 306..319) for this n
    int mt = n >> 4, m = n & 15;
    for (int k = PF_K; k < KP; ++k) {
      size_t idx = ((((size_t)mt * KSTEPS + (k >> 5)) * 4 + ((k >> 3) & 3)) * 16 + m) * 8 + (k & 7);
      pfA[idx] = 0;
    }
  }
  __syncthreads();

  for (int i = 1; i < J_; ++i) {
    if (l < 12) {
      int p = c_parents[i];
      int rr = l >> 2, cc = l & 3;
      float acc = (cc == 3) ? res[w][p][rr * 4 + 3] : 0.f;
#pragma unroll
      for (int k = 0; k < 3; ++k)
        acc += res[w][p][rr * 4 + k] * loc[w][i][k * 4 + cc];
      res[w][i][l] = acc;
    }
    __syncthreads();
  }

  if (l < J_) {
    int j = l;
    float jx = Jp[n * 105 + j * 3 + 0];
    float jy = Jp[n * 105 + j * 3 + 1];
    float jz = Jp[n * 105 + j * 3 + 2];
    float* Ao = Aout + (size_t)n * (J_ * 12) + j * 12;
#pragma unroll
    for (int rr = 0; rr < 3; ++rr) {
      float a0 = res[w][j][rr * 4 + 0];
      float a1 = res[w][j][rr * 4 + 1];
      float a2 = res[w][j][rr * 4 + 2];
      float a3 = res[w][j][rr * 4 + 3];
      Ao[rr * 4 + 0] = a0;
      Ao[rr * 4 + 1] = a1;
      Ao[rr * 4 + 2] = a2;
      Ao[rr * 4 + 3] = a3 - (a0 * jx + a1 * jy + a2 * jz);
    }
  }
}

// ===== v_posed += pf @ pd via bf16 MFMA (no LDS, no barriers) ===============
__global__ __launch_bounds__(256) void k_vposed_mfma(
    const unsigned short* __restrict__ pfA, const unsigned short* __restrict__ pdT,
    float* __restrict__ VS) {
  int t = threadIdx.x;
  int wv = t >> 6, lane = t & 63;
  int q = lane >> 4, col = lane & 15;
  int mtg0 = blockIdx.y * 2;
  int ebase = blockIdx.x * 256 + wv * 64;

  const short8* Ap = (const short8*)pfA;
  const short8* Bp = (const short8*)pdT;

  f32x4 acc[2][4];
#pragma unroll
  for (int mt = 0; mt < 2; ++mt)
#pragma unroll
    for (int et = 0; et < 4; ++et) acc[mt][et] = (f32x4){0.f, 0.f, 0.f, 0.f};

#pragma unroll
  for (int ks = 0; ks < KSTEPS; ++ks) {
    short8 a[2];
#pragma unroll
    for (int mt = 0; mt < 2; ++mt)
      a[mt] = Ap[(((mtg0 + mt) * KSTEPS + ks) * 4 + q) * 16 + col];
    short8 b[4];
#pragma unroll
    for (int et = 0; et < 4; ++et)
      b[et] = Bp[(size_t)(ebase + et * 16 + col) * (KP / 8) + ks * 4 + q];
#pragma unroll
    for (int mt = 0; mt < 2; ++mt)
#pragma unroll
      for (int et = 0; et < 4; ++et)
        acc[mt][et] = __builtin_amdgcn_mfma_f32_16x16x32_bf16(a[mt], b[et], acc[mt][et], 0, 0, 0);
  }

#pragma unroll
  for (int mt = 0; mt < 2; ++mt) {
#pragma unroll
    for (int et = 0; et < 4; ++et) {
      int e = ebase + et * 16 + col;
      if (e < V3) {
#pragma unroll
        for (int r = 0; r < 4; ++r) {
          int n = (mtg0 + mt) * 16 + q * 4 + r;
          size_t off = (size_t)n * V3 + e;
          VS[off] += acc[mt][et][r];
        }
      }
    }
  }
}

// ===== skinning (2 bodies per block): verts = (sum_j w*A)@[v_posed,1]+trans =
__global__ __launch_bounds__(256) void k_skin4(
    const float* __restrict__ Aw, const float* __restrict__ wtsT,
    const float* __restrict__ trans, float* __restrict__ VT) {
  int n0 = blockIdx.y * 2;
  int v = blockIdx.x * 256 + threadIdx.x;
  if (v >= V_) return;
  const float* A0 = Aw + (size_t)n0 * (J_ * 12);       // uniform -> s_load
  const float* A1 = A0 + (J_ * 12);
  float T0[12], T1[12];
#pragma unroll
  for (int k = 0; k < 12; ++k) { T0[k] = 0.f; T1[k] = 0.f; }
#pragma unroll
  for (int j = 0; j < J_; ++j) {
    float wj = wtsT[(size_t)j * V_ + v];               // coalesced, shared by both n
#pragma unroll
    for (int k = 0; k < 12; ++k) {
      T0[k] += wj * A0[j * 12 + k];
      T1[k] += wj * A1[j * 12 + k];
    }
  }
#pragma unroll
  for (int nn = 0; nn < 2; ++nn) {
    int n = n0 + nn;
    const float* T = nn ? T1 : T0;
    float* p = VT + (size_t)n * V3 + 3 * v;
    float x = p[0], y = p[1], z = p[2];
    float tx = trans[n * 3 + 0], ty = trans[n * 3 + 1], tz = trans[n * 3 + 2];
    p[0] = T[0] * x + T[1] * y + T[2]  * z + T[3]  + tx;
    p[1] = T[4] * x + T[5] * y + T[6]  * z + T[7]  + ty;
    p[2] = T[8] * x + T[9] * y + T[10] * z + T[11] + tz;
  }
}

extern "C" void kernel_launch(void* const* d_in, const int* in_sizes, int n_in,
                              void* d_out, int out_size, void* d_ws, size_t ws_size,
                              hipStream_t stream) {
  const float* beta   = (const float*)d_in[0];
  const float* theta  = (const float*)d_in[1];
  const float* se     = (const float*)d_in[2];
  const float* deform = (const float*)d_in[3];
  const float* trans  = (const float*)d_in[4];
  const float* vt     = (const float*)d_in[5];
  const float* sd     = (const float*)d_in[6];
  const float* pd     = (const float*)d_in[7];
  const float* Jr     = (const float*)d_in[8];
  const float* wts    = (const float*)d_in[9];

  float* out    = (float*)d_out;
  float* verts  = out;                               // N*V3 (v_shaped/v_posed buffer)
  float* joints = out + (size_t)N_ * V3;             // N*105
  float* Rs     = joints + (size_t)N_ * 105;         // N*315

  char* w = (char*)d_ws;
  unsigned short* pdT   = (unsigned short*)w;                    // EP*KP*2   = 7,536,640 B
  unsigned short* pfA   = (unsigned short*)(w + 7536640);        // 512*320*2 =   327,680 B
  float* Jp    = (float*)(w + 7864320);                          // 512*105*4 =   215,040 B
  float* Aw    = (float*)(w + 8079360);                          // 512*420*4 =   860,160 B
  float* JrT36 = (float*)(w + 8939520);                          // 36*V*4    =   560,016 B
  float* wtsT  = (float*)(w + 9499536);                          // 35*V*4    =   544,460 B

  k_prep_all<<<PREP_BLOCKS, 256, 0, stream>>>(beta, deform, vt, sd, Jr, wts, pd,
                                              verts, JrT36, wtsT, pdT);
  k_jreduce4<<<N_, 256, 0, stream>>>(verts, JrT36, Jp);
  k_chain_rod<<<N_ / 4, 256, 0, stream>>>(theta, Jp, se, Rs, pfA, Aw);
  k_vposed_mfma<<<dim3(46, N_ / 32), 256, 0, stream>>>(pfA, pdT, verts);
  k_skin4<<<dim3(16, N_ / 2), 256, 0, stream>>>(Aw, wtsT, trans, verts);
  k_jreduce4<<<N_, 256, 0, stream>>>(verts, JrT36, joints);
}

// Round 7
// 266.732 us; speedup vs baseline: 1.1013x; 1.1013x over previous
//
#include <hip/hip_runtime.h>

#define N_   512
#define V_   3889
#define V3   11667      // V_*3
#define J_   35
#define NB_  20
#define PF_K 306        // 34*9
#define KP   320        // K padded to 10 MFMA k-steps of 32
#define KSTEPS 10
#define EP   11776      // 46*256, e padded
#define VP16 3904       // V padded to 244 16-tiles

typedef __attribute__((ext_vector_type(8))) short short8;
typedef __attribute__((ext_vector_type(4))) float f32x4;

__constant__ int c_parents[J_] = {0,0,1,2,3,4,5,6,7,8,9,6,11,12,13,6,15,16,17,18,
                                  16,20,21,22,23,16,25,26,27,28,29,30,16,1,1};

static __device__ __forceinline__ unsigned short f2bf(float x) {
  union { float f; unsigned int u; } v; v.f = x;
  unsigned int r = v.u + 0x7FFF + ((v.u >> 16) & 1);   // round-to-nearest-even
  return (unsigned short)(r >> 16);
}

// ===== prep (one dispatch, grid-partitioned) =================================
//  A: v_shaped = v_template + deform + beta @ shapedirs
//  B: JrT36[j][v] = Jr[v][j] (rows 35 = 0)
//  C: wtsB[v][64] bf16 = wts[v][j], j-pad + v-pad zeroed (skin B-operand)
//  D: pdT[e][KP] bf16 transpose+pack of posedirs
#define VS_G 4
#define PREP_VS  (46 * (N_ / VS_G))               // 5888
#define PREP_JRT ((36 * V_ + 255) / 256)          // 547
#define PREP_WTS (VP16 / 16)                      // 244
#define PREP_PD  (EP / 64)                        // 184
#define PREP_BLOCKS (PREP_VS + PREP_JRT + PREP_WTS + PREP_PD)
__global__ __launch_bounds__(256) void k_prep_all(
    const float* __restrict__ beta, const float* __restrict__ deform,
    const float* __restrict__ vt,   const float* __restrict__ sd,
    const float* __restrict__ Jr,   const float* __restrict__ wts,
    const float* __restrict__ pd,
    float* __restrict__ VS, float* __restrict__ JrT36,
    unsigned short* __restrict__ wtsB, unsigned short* __restrict__ pdT) {
  int b = blockIdx.x;
  int t = threadIdx.x;
  if (b < PREP_VS) {                       // ---- v_shaped ----
    int e  = (b % 46) * 256 + t;
    int n0 = (b / 46) * VS_G;
    if (e >= V3) return;
    float base = vt[e];
    float acc[VS_G];
#pragma unroll
    for (int i = 0; i < VS_G; ++i) acc[i] = base + deform[(size_t)(n0 + i) * V3 + e];
#pragma unroll
    for (int bb = 0; bb < NB_; ++bb) {
      float sv = sd[(size_t)bb * V3 + e];
#pragma unroll
      for (int i = 0; i < VS_G; ++i) acc[i] += beta[(n0 + i) * NB_ + bb] * sv;
    }
#pragma unroll
    for (int i = 0; i < VS_G; ++i) VS[(size_t)(n0 + i) * V3 + e] = acc[i];
  } else if (b < PREP_VS + PREP_JRT) {     // ---- JrT36 ----
    int idx = (b - PREP_VS) * 256 + t;
    if (idx >= 36 * V_) return;
    int j = idx / V_, v = idx % V_;
    JrT36[idx] = (j < J_) ? Jr[v * J_ + j] : 0.f;
  } else if (b < PREP_VS + PREP_JRT + PREP_WTS) {   // ---- wtsB bf16 ----
    int bb = b - PREP_VS - PREP_JRT;
    int v   = bb * 16 + (t >> 4);
    int jk0 = (t & 15) * 4;
    unsigned short pk[4];
#pragma unroll
    for (int i = 0; i < 4; ++i) {
      int j = jk0 + i;
      float x = (v < V_ && j < J_) ? wts[(size_t)v * J_ + j] : 0.f;
      pk[i] = f2bf(x);
    }
    *(unsigned long long*)(wtsB + (size_t)v * 64 + jk0) =
        *(unsigned long long*)pk;
  } else {                                 // ---- pdT bf16 ----
    int bb = b - PREP_VS - PREP_JRT - PREP_WTS;
    int e  = bb * 64 + (t & 63);
    int kg = t >> 6;
    bool ev = e < V3;
    for (int kk = 0; kk < 80; kk += 8) {
      int k0 = kg * 80 + kk;
      union { unsigned short u[8]; short8 s; } pk;
#pragma unroll
      for (int ii = 0; ii < 8; ++ii) {
        int k = k0 + ii;
        float x = (ev && k < PF_K) ? pd[(size_t)k * V3 + e] : 0.f;
        pk.u[ii] = f2bf(x);
      }
      *(short8*)(pdT + (size_t)e * KP + k0) = pk.s;
    }
  }
}

// ===== dst[n,j,c] = sum_v src[n,v,c] * JrT36[j,v] ===========================
// 512-thread blocks: 8 waves = 4 j-groups x 2 v-halves; LDS combine.
#define JR5_JG 9
__global__ __launch_bounds__(512) void k_jreduce5(
    const float* __restrict__ src, const float* __restrict__ JrT36,
    float* __restrict__ dst) {
  __shared__ float part[8][27];
  int t = threadIdx.x;
  int lane = t & 63;
  int w = t >> 6;              // 0..7
  int jg = w & 3, vh = w >> 2;
  int n = blockIdx.x;
  int j0 = jg * JR5_JG;
  const float* s0 = src + (size_t)n * V3;

  float acc[JR5_JG][3];
#pragma unroll
  for (int jj = 0; jj < JR5_JG; ++jj)
#pragma unroll
    for (int cc = 0; cc < 3; ++cc) acc[jj][cc] = 0.f;

  int iv0 = vh * 31;
  int ivn = vh ? 30 : 31;      // 31+30 = 61 covers V_
#pragma unroll 2
  for (int i = 0; i < ivn; ++i) {
    int v = (iv0 + i) * 64 + lane;
    bool ok = v < V_;
    float jr[JR5_JG];
#pragma unroll
    for (int jj = 0; jj < JR5_JG; ++jj)
      jr[jj] = ok ? JrT36[(size_t)(j0 + jj) * V_ + v] : 0.f;
    float sx = ok ? s0[3 * v + 0] : 0.f;
    float sy = ok ? s0[3 * v + 1] : 0.f;
    float sz = ok ? s0[3 * v + 2] : 0.f;
#pragma unroll
    for (int jj = 0; jj < JR5_JG; ++jj) {
      acc[jj][0] += jr[jj] * sx;
      acc[jj][1] += jr[jj] * sy;
      acc[jj][2] += jr[jj] * sz;
    }
  }

#pragma unroll
  for (int jj = 0; jj < JR5_JG; ++jj)
#pragma unroll
    for (int cc = 0; cc < 3; ++cc) {
      float v = acc[jj][cc];
#pragma unroll
      for (int off = 32; off > 0; off >>= 1)
        v += __shfl_down(v, off, 64);
      if (lane == 0) part[w][jj * 3 + cc] = v;
    }
  __syncthreads();

  if (t < 108) {
    int g = t / 27, idx = t % 27;
    int j = g * JR5_JG + idx / 3;
    if (j < J_)
      dst[n * 105 + j * 3 + idx % 3] = part[g][idx] + part[g + 4][idx];
  }
}

// ===== Rodrigues + chain -> Rs, pfA(bf16 A-frag), AwB(bf16, trans folded) ===
// pfA: [mt=n>>4][ks][q][m=n&15][8].  AwB: [n][dim 16][j 64] (j-pad zeroed).
__global__ __launch_bounds__(256) void k_chain_rod(
    const float* __restrict__ theta, const float* __restrict__ Jp,
    const float* __restrict__ se,    const float* __restrict__ trans,
    float* __restrict__ Rs_out, unsigned short* __restrict__ pfA,
    unsigned short* __restrict__ AwB) {
  __shared__ float loc[4][J_][12];
  __shared__ float res[4][J_][12];
  int t = threadIdx.x;
  int w = t >> 6, l = t & 63;
  int n = blockIdx.x * 4 + w;

  if (l < J_) {
    int j = l;
    const float* th = theta + n * (J_ * 3) + j * 3;
    float t0 = th[0], t1 = th[1], t2 = th[2];
    float angle = sqrtf(t0 * t0 + t1 * t1 + t2 * t2 + 1e-8f);
    float inv = 1.0f / angle;
    float r0 = t0 * inv, r1 = t1 * inv, r2 = t2 * inv;
    float s, c;
    sincosf(angle, &s, &c);
    float omc = 1.0f - c;
    float r[9];
    r[0] = c + omc * r0 * r0;      r[1] = omc * r0 * r1 - s * r2;  r[2] = omc * r0 * r2 + s * r1;
    r[3] = omc * r1 * r0 + s * r2; r[4] = c + omc * r1 * r1;       r[5] = omc * r1 * r2 - s * r0;
    r[6] = omc * r2 * r0 - s * r1; r[7] = omc * r2 * r1 + s * r0;  r[8] = c + omc * r2 * r2;

    float* ro = Rs_out + (size_t)n * (J_ * 9) + j * 9;
#pragma unroll
    for (int k = 0; k < 9; ++k) ro[k] = r[k];
    if (j > 0) {
      int mt = n >> 4, m = n & 15;
#pragma unroll
      for (int kk = 0; kk < 9; ++kk) {
        int k = (j - 1) * 9 + kk;
        float v = r[kk] - ((kk == 0 || kk == 4 || kk == 8) ? 1.0f : 0.0f);
        size_t idx = ((((size_t)mt * KSTEPS + (k >> 5)) * 4 + ((k >> 3) & 3)) * 16 + m) * 8 + (k & 7);
        pfA[idx] = f2bf(v);
      }
    }

    if (j == 0) {
#pragma unroll
      for (int rr = 0; rr < 3; ++rr) {
        loc[w][0][rr * 4 + 0] = r[rr * 3 + 0];
        loc[w][0][rr * 4 + 1] = r[rr * 3 + 1];
        loc[w][0][rr * 4 + 2] = r[rr * 3 + 2];
        loc[w][0][rr * 4 + 3] = Jp[n * 105 + rr];
      }
#pragma unroll
      for (int k = 0; k < 12; ++k) res[w][0][k] = loc[w][0][k];
    } else {
      int p = c_parents[j];
      float si[3], sp[3], jh[3];
#pragma unroll
      for (int cidx = 0; cidx < 3; ++cidx) {
        si[cidx] = se[n * 105 + j * 3 + cidx];
        sp[cidx] = se[n * 105 + p * 3 + cidx];
        jh[cidx] = Jp[n * 105 + j * 3 + cidx] - Jp[n * 105 + p * 3 + cidx];
      }
#pragma unroll
      for (int rr = 0; rr < 3; ++rr) {
        float invp = 1.0f / sp[rr];
        loc[w][j][rr * 4 + 0] = r[rr * 3 + 0] * si[0] * invp;
        loc[w][j][rr * 4 + 1] = r[rr * 3 + 1] * si[1] * invp;
        loc[w][j][rr * 4 + 2] = r[rr * 3 + 2] * si[2] * invp;
        loc[w][j][rr * 4 + 3] = jh[rr];
      }
    }
  } else {
    // lanes 35..63: zero AwB j-pad column l (all 16 dims)
    unsigned short* An = AwB + (size_t)n * 16 * 64 + l;
#pragma unroll
    for (int d = 0; d < 16; ++d) An[d * 64] = 0;
    if (l == 40) {
      // zero pfA k-pad (k = 306..319) for this n
      int mt = n >> 4, m = n & 15;
      for (int k = PF_K; k < KP; ++k) {
        size_t idx = ((((size_t)mt * KSTEPS + (k >> 5)) * 4 + ((k >> 3) & 3)) * 16 + m) * 8 + (k & 7);
        pfA[idx] = 0;
      }
    }
  }
  __syncthreads();

  for (int i = 1; i < J_; ++i) {
    if (l < 12) {
      int p = c_parents[i];
      int rr = l >> 2, cc = l & 3;
      float acc = (cc == 3) ? res[w][p][rr * 4 + 3] : 0.f;
#pragma unroll
      for (int k = 0; k < 3; ++k)
        acc += res[w][p][rr * 4 + k] * loc[w][i][k * 4 + cc];
      res[w][i][l] = acc;
    }
    __syncthreads();
  }

  if (l < J_) {
    int j = l;
    float jx = Jp[n * 105 + j * 3 + 0];
    float jy = Jp[n * 105 + j * 3 + 1];
    float jz = Jp[n * 105 + j * 3 + 2];
    unsigned short* An = AwB + (size_t)n * 16 * 64 + j;   // column j
#pragma unroll
    for (int rr = 0; rr < 3; ++rr) {
      float a0 = res[w][j][rr * 4 + 0];
      float a1 = res[w][j][rr * 4 + 1];
      float a2 = res[w][j][rr * 4 + 2];
      float a3 = res[w][j][rr * 4 + 3] - (a0 * jx + a1 * jy + a2 * jz)
               + trans[n * 3 + rr];                       // fold trans (sum w = 1)
      An[(rr * 4 + 0) * 64] = f2bf(a0);
      An[(rr * 4 + 1) * 64] = f2bf(a1);
      An[(rr * 4 + 2) * 64] = f2bf(a2);
      An[(rr * 4 + 3) * 64] = f2bf(a3);
    }
  }
}

// ===== v_posed += pf @ pd via bf16 MFMA (no LDS, no barriers) ===============
__global__ __launch_bounds__(256) void k_vposed_mfma(
    const unsigned short* __restrict__ pfA, const unsigned short* __restrict__ pdT,
    float* __restrict__ VS) {
  int t = threadIdx.x;
  int wv = t >> 6, lane = t & 63;
  int q = lane >> 4, col = lane & 15;
  int mtg0 = blockIdx.y * 2;
  int ebase = blockIdx.x * 256 + wv * 64;

  const short8* Ap = (const short8*)pfA;
  const short8* Bp = (const short8*)pdT;

  f32x4 acc[2][4];
#pragma unroll
  for (int mt = 0; mt < 2; ++mt)
#pragma unroll
    for (int et = 0; et < 4; ++et) acc[mt][et] = (f32x4){0.f, 0.f, 0.f, 0.f};

#pragma unroll
  for (int ks = 0; ks < KSTEPS; ++ks) {
    short8 a[2];
#pragma unroll
    for (int mt = 0; mt < 2; ++mt)
      a[mt] = Ap[(((mtg0 + mt) * KSTEPS + ks) * 4 + q) * 16 + col];
    short8 b[4];
#pragma unroll
    for (int et = 0; et < 4; ++et)
      b[et] = Bp[(size_t)(ebase + et * 16 + col) * (KP / 8) + ks * 4 + q];
#pragma unroll
    for (int mt = 0; mt < 2; ++mt)
#pragma unroll
      for (int et = 0; et < 4; ++et)
        acc[mt][et] = __builtin_amdgcn_mfma_f32_16x16x32_bf16(a[mt], b[et], acc[mt][et], 0, 0, 0);
  }

#pragma unroll
  for (int mt = 0; mt < 2; ++mt) {
#pragma unroll
    for (int et = 0; et < 4; ++et) {
      int e = ebase + et * 16 + col;
      if (e < V3) {
#pragma unroll
        for (int r = 0; r < 4; ++r) {
          int n = (mtg0 + mt) * 16 + q * 4 + r;
          size_t off = (size_t)n * V3 + e;
          VS[off] += acc[mt][et][r];
        }
      }
    }
  }
}

// ===== skinning via MFMA: D[dim][v] = A_n[dim][j] @ wts[j][v] ===============
// M=16 dims, N=16 v per wave, K=64 (j pad). C-layout: col=lane&15=v,
// rows q*4+reg = dims -> quad q computes verts component q locally.
#define SK_NG 16    // n-groups -> N_/16 = 32 n per block
__global__ __launch_bounds__(256) void k_skin_mfma(
    const unsigned short* __restrict__ AwB, const unsigned short* __restrict__ wtsB,
    float* __restrict__ VS) {
  int t = threadIdx.x;
  int wv = t >> 6, lane = t & 63;
  int q = lane >> 4, col = lane & 15;
  int vtile = blockIdx.x * 4 + wv;        // 0..243
  int v = vtile * 16 + col;
  int n0 = blockIdx.y * (N_ / SK_NG);

  const short8* Bp = (const short8*)(wtsB + (size_t)v * 64);
  short8 b0 = Bp[q];                      // ks=0: k = q*8
  short8 b1 = Bp[4 + q];                  // ks=1: k = 32 + q*8
  bool vok = (v < V_) && (q < 3);

#pragma unroll 2
  for (int ni = 0; ni < N_ / SK_NG; ++ni) {
    int n = n0 + ni;
    const short8* Ap = (const short8*)(AwB + ((size_t)n * 16 + col) * 64);
    short8 a0 = Ap[q];
    short8 a1 = Ap[4 + q];
    f32x4 acc = (f32x4){0.f, 0.f, 0.f, 0.f};
    acc = __builtin_amdgcn_mfma_f32_16x16x32_bf16(a0, b0, acc, 0, 0, 0);
    acc = __builtin_amdgcn_mfma_f32_16x16x32_bf16(a1, b1, acc, 0, 0, 0);
    if (vok) {
      float* p = VS + (size_t)n * V3 + 3 * v;
      float x = p[0], y = p[1], z = p[2];
      p[q] = acc[0] * x + acc[1] * y + acc[2] * z + acc[3];
    }
  }
}

extern "C" void kernel_launch(void* const* d_in, const int* in_sizes, int n_in,
                              void* d_out, int out_size, void* d_ws, size_t ws_size,
                              hipStream_t stream) {
  const float* beta   = (const float*)d_in[0];
  const float* theta  = (const float*)d_in[1];
  const float* se     = (const float*)d_in[2];
  const float* deform = (const float*)d_in[3];
  const float* trans  = (const float*)d_in[4];
  const float* vt     = (const float*)d_in[5];
  const float* sd     = (const float*)d_in[6];
  const float* pd     = (const float*)d_in[7];
  const float* Jr     = (const float*)d_in[8];
  const float* wts    = (const float*)d_in[9];

  float* out    = (float*)d_out;
  float* verts  = out;                               // N*V3 (v_shaped/v_posed buffer)
  float* joints = out + (size_t)N_ * V3;             // N*105
  float* Rs     = joints + (size_t)N_ * 105;         // N*315

  char* w = (char*)d_ws;
  unsigned short* pdT   = (unsigned short*)w;                    // 7,536,640 B
  unsigned short* pfA   = (unsigned short*)(w + 7536640);        //   327,680 B
  float* Jp    = (float*)(w + 7864320);                          //   215,040 B
  unsigned short* AwB   = (unsigned short*)(w + 8079360);        // 1,048,576 B
  float* JrT36 = (float*)(w + 9127936);                          //   560,016 B
  unsigned short* wtsB  = (unsigned short*)(w + 9687952);        //   499,712 B

  k_prep_all<<<PREP_BLOCKS, 256, 0, stream>>>(beta, deform, vt, sd, Jr, wts, pd,
                                              verts, JrT36, wtsB, pdT);
  k_jreduce5<<<N_, 512, 0, stream>>>(verts, JrT36, Jp);
  k_chain_rod<<<N_ / 4, 256, 0, stream>>>(theta, Jp, se, trans, Rs, pfA, AwB);
  k_vposed_mfma<<<dim3(46, N_ / 32), 256, 0, stream>>>(pfA, pdT, verts);
  k_skin_mfma<<<dim3(61, SK_NG), 256, 0, stream>>>(AwB, wtsB, verts);
  k_jreduce5<<<N_, 512, 0, stream>>>(verts, JrT36, joints);
}

// Round 8
// 256.046 us; speedup vs baseline: 1.1473x; 1.0417x over previous
//
#include <hip/hip_runtime.h>

#define N_   512
#define V_   3889
#define V3   11667      // V_*3
#define J_   35
#define NB_  20
#define PF_K 306        // 34*9
#define KP2  352        // K = [pf 306 | beta 20 | pad 26], 11 k-steps of 32
#define KS2  11
#define EP2  11776      // pdT rows (fused kernel reads e up to 11775)
#define WROWS 3920      // wtsB rows (49*80 = 3920 v-slots)

typedef __attribute__((ext_vector_type(8))) short short8;
typedef __attribute__((ext_vector_type(4))) float f32x4;

__constant__ int c_parents[J_] = {0,0,1,2,3,4,5,6,7,8,9,6,11,12,13,6,15,16,17,18,
                                  16,20,21,22,23,16,25,26,27,28,29,30,16,1,1};

static __device__ __forceinline__ unsigned short f2bf(float x) {
  union { float f; unsigned int u; } v; v.f = x;
  unsigned int r = v.u + 0x7FFF + ((v.u >> 16) & 1);   // round-to-nearest-even
  return (unsigned short)(r >> 16);
}

// ===== prep (grid-partitioned): ==============================================
//  A: JrT36[j][v] = Jr[v][j] (row 35 = 0)
//  B: wtsB[v][64] bf16 (j-pad, v-pad to WROWS zeroed)
//  C: pdT[e][KP2] bf16 = [posedirs | shapedirs | 0] transposed
//  D: 21 small row-reductions: vtJr[105] = vt@Jr, sdJr[b][105] = sd_b@Jr
#define PREP_JRT ((36 * V_ + 255) / 256)          // 547
#define PREP_WTS (WROWS / 16)                     // 245
#define PREP_PD  (EP2 / 64)                       // 184
#define PREP_SR  21
#define PREP_BLOCKS (PREP_JRT + PREP_WTS + PREP_PD + PREP_SR)
__global__ __launch_bounds__(256) void k_prep2(
    const float* __restrict__ Jr,  const float* __restrict__ wts,
    const float* __restrict__ pd,  const float* __restrict__ sd,
    const float* __restrict__ vt,
    float* __restrict__ JrT36, unsigned short* __restrict__ wtsB,
    unsigned short* __restrict__ pdT,
    float* __restrict__ vtJr, float* __restrict__ sdJr) {
  int b = blockIdx.x;
  int t = threadIdx.x;
  if (b < PREP_JRT) {                      // ---- JrT36 ----
    int idx = b * 256 + t;
    if (idx >= 36 * V_) return;
    int j = idx / V_, v = idx % V_;
    JrT36[idx] = (j < J_) ? Jr[v * J_ + j] : 0.f;
  } else if (b < PREP_JRT + PREP_WTS) {    // ---- wtsB bf16 ----
    int bb = b - PREP_JRT;
    int v   = bb * 16 + (t >> 4);
    int jk0 = (t & 15) * 4;
    unsigned short pk[4];
#pragma unroll
    for (int i = 0; i < 4; ++i) {
      int j = jk0 + i;
      float x = (v < V_ && j < J_) ? wts[(size_t)v * J_ + j] : 0.f;
      pk[i] = f2bf(x);
    }
    *(unsigned long long*)(wtsB + (size_t)v * 64 + jk0) = *(unsigned long long*)pk;
  } else if (b < PREP_JRT + PREP_WTS + PREP_PD) {   // ---- pdT bf16 ----
    int bb = b - PREP_JRT - PREP_WTS;
    int e  = bb * 64 + (t & 63);
    int kg = t >> 6;                       // 0..3, each covers 88 k
    bool ev = e < V3;
    for (int kk = 0; kk < 88; kk += 8) {
      int k0 = kg * 88 + kk;
      union { unsigned short u[8]; short8 s; } pk;
#pragma unroll
      for (int ii = 0; ii < 8; ++ii) {
        int k = k0 + ii;
        float x = 0.f;
        if (ev && k < PF_K)        x = pd[(size_t)k * V3 + e];
        else if (ev && k < PF_K + NB_) x = sd[(size_t)(k - PF_K) * V3 + e];
        pk.u[ii] = f2bf(x);
      }
      *(short8*)(pdT + (size_t)e * KP2 + k0) = pk.s;
    }
  } else {                                 // ---- vtJr / sdJr row reductions ----
    int bb = b - PREP_JRT - PREP_WTS - PREP_PD;   // 0..20
    const float* src = (bb == 0) ? vt : sd + (size_t)(bb - 1) * V3;
    float* dst = (bb == 0) ? vtJr : sdJr + (size_t)(bb - 1) * 105;
    int lane = t & 63;
    int j0 = (t >> 6) * 9;                 // 4 waves x 9 j
    float acc[9][3];
#pragma unroll
    for (int jj = 0; jj < 9; ++jj)
#pragma unroll
      for (int cc = 0; cc < 3; ++cc) acc[jj][cc] = 0.f;
#pragma unroll 2
    for (int iv = 0; iv < (V_ + 63) / 64; ++iv) {
      int v = iv * 64 + lane;
      bool ok = v < V_;
      float jr[9];
#pragma unroll
      for (int jj = 0; jj < 9; ++jj)
        jr[jj] = ok ? JrT36[(size_t)(j0 + jj) * V_ + v] : 0.f;
      float sx = ok ? src[3 * v + 0] : 0.f;
      float sy = ok ? src[3 * v + 1] : 0.f;
      float sz = ok ? src[3 * v + 2] : 0.f;
#pragma unroll
      for (int jj = 0; jj < 9; ++jj) {
        acc[jj][0] += jr[jj] * sx;
        acc[jj][1] += jr[jj] * sy;
        acc[jj][2] += jr[jj] * sz;
      }
    }
#pragma unroll
    for (int jj = 0; jj < 9; ++jj)
#pragma unroll
      for (int cc = 0; cc < 3; ++cc) {
        float v = acc[jj][cc];
#pragma unroll
        for (int off = 32; off > 0; off >>= 1)
          v += __shfl_down(v, off, 64);
        acc[jj][cc] = v;
      }
    if (lane == 0) {
#pragma unroll
      for (int jj = 0; jj < 9; ++jj) {
        int j = j0 + jj;
        if (j < J_)
#pragma unroll
          for (int cc = 0; cc < 3; ++cc) dst[j * 3 + cc] = acc[jj][cc];
      }
    }
  }
}

// NOTE: this kernel's JrT36 read races with part A in the same dispatch? No —
// part D reads JrT36 written by part A *in the same kernel launch*: NOT safe.
// Fix: part D reads Jr directly (strided) instead of JrT36.

// ===== jreduce (shared shape): dst[n,jc] = sum_v src[n,3v+c]*JrT36[j,v] =====
#define JR5_JG 9
__global__ __launch_bounds__(512) void k_jreduce5(
    const float* __restrict__ src, const float* __restrict__ JrT36,
    float* __restrict__ dst) {
  __shared__ float part[8][27];
  int t = threadIdx.x;
  int lane = t & 63;
  int w = t >> 6;
  int jg = w & 3, vh = w >> 2;
  int n = blockIdx.x;
  int j0 = jg * JR5_JG;
  const float* s0 = src + (size_t)n * V3;

  float acc[JR5_JG][3];
#pragma unroll
  for (int jj = 0; jj < JR5_JG; ++jj)
#pragma unroll
    for (int cc = 0; cc < 3; ++cc) acc[jj][cc] = 0.f;

  int iv0 = vh * 31;
  int ivn = vh ? 30 : 31;
#pragma unroll 2
  for (int i = 0; i < ivn; ++i) {
    int v = (iv0 + i) * 64 + lane;
    bool ok = v < V_;
    float jr[JR5_JG];
#pragma unroll
    for (int jj = 0; jj < JR5_JG; ++jj)
      jr[jj] = ok ? JrT36[(size_t)(j0 + jj) * V_ + v] : 0.f;
    float sx = ok ? s0[3 * v + 0] : 0.f;
    float sy = ok ? s0[3 * v + 1] : 0.f;
    float sz = ok ? s0[3 * v + 2] : 0.f;
#pragma unroll
    for (int jj = 0; jj < JR5_JG; ++jj) {
      acc[jj][0] += jr[jj] * sx;
      acc[jj][1] += jr[jj] * sy;
      acc[jj][2] += jr[jj] * sz;
    }
  }

#pragma unroll
  for (int jj = 0; jj < JR5_JG; ++jj)
#pragma unroll
    for (int cc = 0; cc < 3; ++cc) {
      float v = acc[jj][cc];
#pragma unroll
      for (int off = 32; off > 0; off >>= 1)
        v += __shfl_down(v, off, 64);
      if (lane == 0) part[w][jj * 3 + cc] = v;
    }
  __syncthreads();

  if (t < 108) {
    int g = t / 27, idx = t % 27;
    int j = g * JR5_JG + idx / 3;
    if (j < J_)
      dst[n * 105 + j * 3 + idx % 3] = part[g][idx] + part[g + 4][idx];
  }
}

// ===== Jp = deform@Jr + vtJr + beta @ sdJr ==================================
__global__ __launch_bounds__(512) void k_jp(
    const float* __restrict__ deform, const float* __restrict__ JrT36,
    const float* __restrict__ vtJr,   const float* __restrict__ sdJr,
    const float* __restrict__ beta,   float* __restrict__ Jp) {
  __shared__ float part[8][27];
  int t = threadIdx.x;
  int lane = t & 63;
  int w = t >> 6;
  int jg = w & 3, vh = w >> 2;
  int n = blockIdx.x;
  int j0 = jg * JR5_JG;
  const float* s0 = deform + (size_t)n * V3;

  float acc[JR5_JG][3];
#pragma unroll
  for (int jj = 0; jj < JR5_JG; ++jj)
#pragma unroll
    for (int cc = 0; cc < 3; ++cc) acc[jj][cc] = 0.f;

  int iv0 = vh * 31;
  int ivn = vh ? 30 : 31;
#pragma unroll 2
  for (int i = 0; i < ivn; ++i) {
    int v = (iv0 + i) * 64 + lane;
    bool ok = v < V_;
    float jr[JR5_JG];
#pragma unroll
    for (int jj = 0; jj < JR5_JG; ++jj)
      jr[jj] = ok ? JrT36[(size_t)(j0 + jj) * V_ + v] : 0.f;
    float sx = ok ? s0[3 * v + 0] : 0.f;
    float sy = ok ? s0[3 * v + 1] : 0.f;
    float sz = ok ? s0[3 * v + 2] : 0.f;
#pragma unroll
    for (int jj = 0; jj < JR5_JG; ++jj) {
      acc[jj][0] += jr[jj] * sx;
      acc[jj][1] += jr[jj] * sy;
      acc[jj][2] += jr[jj] * sz;
    }
  }

#pragma unroll
  for (int jj = 0; jj < JR5_JG; ++jj)
#pragma unroll
    for (int cc = 0; cc < 3; ++cc) {
      float v = acc[jj][cc];
#pragma unroll
      for (int off = 32; off > 0; off >>= 1)
        v += __shfl_down(v, off, 64);
      if (lane == 0) part[w][jj * 3 + cc] = v;
    }
  __syncthreads();

  if (t < 108) {
    int g = t / 27, idx = t % 27;
    int j = g * JR5_JG + idx / 3;
    if (j < J_) {
      int jc = j * 3 + idx % 3;
      float val = part[g][idx] + part[g + 4][idx] + vtJr[jc];
      const float* bn = beta + n * NB_;
#pragma unroll
      for (int bb = 0; bb < NB_; ++bb)
        val += bn[bb] * sdJr[bb * 105 + jc];
      Jp[n * 105 + jc] = val;
    }
  }
}

// ===== Rodrigues + chain -> Rs, pfA([pf|beta|0] bf16 A-frag), AwB ===========
// pfA: [mt=n>>4][ks][q][m=n&15][o] with KS2=11.  AwB: [n][dim16][j64].
__global__ __launch_bounds__(256) void k_chain_rod(
    const float* __restrict__ theta, const float* __restrict__ Jp,
    const float* __restrict__ se,    const float* __restrict__ trans,
    const float* __restrict__ beta,
    float* __restrict__ Rs_out, unsigned short* __restrict__ pfA,
    unsigned short* __restrict__ AwB) {
  __shared__ float loc[4][J_][12];
  __shared__ float res[4][J_][12];
  int t = threadIdx.x;
  int w = t >> 6, l = t & 63;
  int n = blockIdx.x * 4 + w;
  int mt = n >> 4, m = n & 15;

  if (l < J_) {
    int j = l;
    const float* th = theta + n * (J_ * 3) + j * 3;
    float t0 = th[0], t1 = th[1], t2 = th[2];
    float angle = sqrtf(t0 * t0 + t1 * t1 + t2 * t2 + 1e-8f);
    float inv = 1.0f / angle;
    float r0 = t0 * inv, r1 = t1 * inv, r2 = t2 * inv;
    float s, c;
    sincosf(angle, &s, &c);
    float omc = 1.0f - c;
    float r[9];
    r[0] = c + omc * r0 * r0;      r[1] = omc * r0 * r1 - s * r2;  r[2] = omc * r0 * r2 + s * r1;
    r[3] = omc * r1 * r0 + s * r2; r[4] = c + omc * r1 * r1;       r[5] = omc * r1 * r2 - s * r0;
    r[6] = omc * r2 * r0 - s * r1; r[7] = omc * r2 * r1 + s * r0;  r[8] = c + omc * r2 * r2;

    float* ro = Rs_out + (size_t)n * (J_ * 9) + j * 9;
#pragma unroll
    for (int k = 0; k < 9; ++k) ro[k] = r[k];
    if (j > 0) {
#pragma unroll
      for (int kk = 0; kk < 9; ++kk) {
        int k = (j - 1) * 9 + kk;
        float v = r[kk] - ((kk == 0 || kk == 4 || kk == 8) ? 1.0f : 0.0f);
        size_t idx = ((((size_t)mt * KS2 + (k >> 5)) * 4 + ((k >> 3) & 3)) * 16 + m) * 8 + (k & 7);
        pfA[idx] = f2bf(v);
      }
    }

    if (j == 0) {
#pragma unroll
      for (int rr = 0; rr < 3; ++rr) {
        loc[w][0][rr * 4 + 0] = r[rr * 3 + 0];
        loc[w][0][rr * 4 + 1] = r[rr * 3 + 1];
        loc[w][0][rr * 4 + 2] = r[rr * 3 + 2];
        loc[w][0][rr * 4 + 3] = Jp[n * 105 + rr];
      }
#pragma unroll
      for (int k = 0; k < 12; ++k) res[w][0][k] = loc[w][0][k];
    } else {
      int p = c_parents[j];
      float si[3], sp[3], jh[3];
#pragma unroll
      for (int cidx = 0; cidx < 3; ++cidx) {
        si[cidx] = se[n * 105 + j * 3 + cidx];
        sp[cidx] = se[n * 105 + p * 3 + cidx];
        jh[cidx] = Jp[n * 105 + j * 3 + cidx] - Jp[n * 105 + p * 3 + cidx];
      }
#pragma unroll
      for (int rr = 0; rr < 3; ++rr) {
        float invp = 1.0f / sp[rr];
        loc[w][j][rr * 4 + 0] = r[rr * 3 + 0] * si[0] * invp;
        loc[w][j][rr * 4 + 1] = r[rr * 3 + 1] * si[1] * invp;
        loc[w][j][rr * 4 + 2] = r[rr * 3 + 2] * si[2] * invp;
        loc[w][j][rr * 4 + 3] = jh[rr];
      }
    }
  } else {
    // lanes 35..63: AwB j-pad zero + pfA beta rows + pfA k-pad zeros
    unsigned short* An = AwB + (size_t)n * 16 * 64 + l;
#pragma unroll
    for (int d = 0; d < 16; ++d) An[d * 64] = 0;
    if (l < 55) {                    // beta -> k = 306 + (l-35)
      int k = PF_K + (l - 35);
      size_t idx = ((((size_t)mt * KS2 + (k >> 5)) * 4 + ((k >> 3) & 3)) * 16 + m) * 8 + (k & 7);
      pfA[idx] = f2bf(beta[n * NB_ + (l - 35)]);
    } else {                         // zeros k = 326..351
      for (int k = PF_K + NB_ + (l - 55); k < KP2; k += 9) {
        size_t idx = ((((size_t)mt * KS2 + (k >> 5)) * 4 + ((k >> 3) & 3)) * 16 + m) * 8 + (k & 7);
        pfA[idx] = 0;
      }
    }
  }
  __syncthreads();

  for (int i = 1; i < J_; ++i) {
    if (l < 12) {
      int p = c_parents[i];
      int rr = l >> 2, cc = l & 3;
      float acc = (cc == 3) ? res[w][p][rr * 4 + 3] : 0.f;
#pragma unroll
      for (int k = 0; k < 3; ++k)
        acc += res[w][p][rr * 4 + k] * loc[w][i][k * 4 + cc];
      res[w][i][l] = acc;
    }
    __syncthreads();
  }

  if (l < J_) {
    int j = l;
    float jx = Jp[n * 105 + j * 3 + 0];
    float jy = Jp[n * 105 + j * 3 + 1];
    float jz = Jp[n * 105 + j * 3 + 2];
    unsigned short* An = AwB + (size_t)n * 16 * 64 + j;
#pragma unroll
    for (int rr = 0; rr < 3; ++rr) {
      float a0 = res[w][j][rr * 4 + 0];
      float a1 = res[w][j][rr * 4 + 1];
      float a2 = res[w][j][rr * 4 + 2];
      float a3 = res[w][j][rr * 4 + 3] - (a0 * jx + a1 * jy + a2 * jz)
               + trans[n * 3 + rr];
      An[(rr * 4 + 0) * 64] = f2bf(a0);
      An[(rr * 4 + 1) * 64] = f2bf(a1);
      An[(rr * 4 + 2) * 64] = f2bf(a2);
      An[(rr * 4 + 3) * 64] = f2bf(a3);
    }
  }
}

// ===== fused: v_posed (MFMA, K=352) + LDS stage + skin (MFMA) -> verts ======
// grid(49, 16). Block: 32 n x 256 e computed, 240 e (=80 v) used/written.
#define LSTR 242
__global__ __launch_bounds__(256) void k_vposed_skin(
    const unsigned short* __restrict__ pfA, const unsigned short* __restrict__ pdT,
    const unsigned short* __restrict__ AwB, const unsigned short* __restrict__ wtsB,
    const float* __restrict__ vt, const float* __restrict__ deform,
    float* __restrict__ verts) {
  __shared__ float lds[32 * LSTR];
  int t = threadIdx.x;
  int wv = t >> 6, lane = t & 63;
  int q = lane >> 4, col = lane & 15;
  int bx = blockIdx.x, by = blockIdx.y;
  int mtg0 = by * 2;
  int ebase = bx * 240 + wv * 64;

  const short8* Ap = (const short8*)pfA;
  const short8* Bp = (const short8*)pdT;

  // ---- phase 1: [pf|beta] @ [pd;sd]  (K=352) ----
  f32x4 acc[2][4];
#pragma unroll
  for (int mt = 0; mt < 2; ++mt)
#pragma unroll
    for (int et = 0; et < 4; ++et) acc[mt][et] = (f32x4){0.f, 0.f, 0.f, 0.f};

#pragma unroll
  for (int ks = 0; ks < KS2; ++ks) {
    short8 a[2];
#pragma unroll
    for (int mt = 0; mt < 2; ++mt)
      a[mt] = Ap[(((mtg0 + mt) * KS2 + ks) * 4 + q) * 16 + col];
    short8 b[4];
#pragma unroll
    for (int et = 0; et < 4; ++et)
      b[et] = Bp[(size_t)(ebase + et * 16 + col) * (KP2 / 8) + ks * 4 + q];
#pragma unroll
    for (int mt = 0; mt < 2; ++mt)
#pragma unroll
      for (int et = 0; et < 4; ++et)
        acc[mt][et] = __builtin_amdgcn_mfma_f32_16x16x32_bf16(a[mt], b[et], acc[mt][et], 0, 0, 0);
  }

  // ---- phase 2: += vt + deform, stage v_posed tile into LDS ----
#pragma unroll
  for (int et = 0; et < 4; ++et) {
    int e_loc = wv * 64 + et * 16 + col;
    int e = bx * 240 + e_loc;
    bool ev = (e < V3) && (e_loc < 240);
    float vte = ev ? vt[e] : 0.f;
#pragma unroll
    for (int mt = 0; mt < 2; ++mt) {
#pragma unroll
      for (int r = 0; r < 4; ++r) {
        int n_loc = mt * 16 + q * 4 + r;
        if (ev) {
          int n = by * 32 + n_loc;
          float df = deform[(size_t)n * V3 + e];
          lds[n_loc * LSTR + e_loc] = acc[mt][et][r] + vte + df;
        }
      }
    }
  }
  __syncthreads();

  // ---- phase 3: skin via MFMA, write final verts ----
  short8 bw0[5], bw1[5];
#pragma unroll
  for (int v5 = 0; v5 < 5; ++v5) {
    int v = bx * 80 + v5 * 16 + col;
    const short8* Wp = (const short8*)(wtsB + (size_t)v * 64);
    bw0[v5] = Wp[q];
    bw1[v5] = Wp[4 + q];
  }
#pragma unroll 2
  for (int ni = 0; ni < 8; ++ni) {
    int n_loc = wv * 8 + ni;
    int n = by * 32 + n_loc;
    const short8* Aq = (const short8*)(AwB + ((size_t)n * 16 + col) * 64);
    short8 a0 = Aq[q];
    short8 a1 = Aq[4 + q];
#pragma unroll
    for (int v5 = 0; v5 < 5; ++v5) {
      f32x4 s = (f32x4){0.f, 0.f, 0.f, 0.f};
      s = __builtin_amdgcn_mfma_f32_16x16x32_bf16(a0, bw0[v5], s, 0, 0, 0);
      s = __builtin_amdgcn_mfma_f32_16x16x32_bf16(a1, bw1[v5], s, 0, 0, 0);
      int vl = v5 * 16 + col;
      int v = bx * 80 + vl;
      if (v < V_ && q < 3) {
        float x = lds[n_loc * LSTR + 3 * vl + 0];
        float y = lds[n_loc * LSTR + 3 * vl + 1];
        float z = lds[n_loc * LSTR + 3 * vl + 2];
        verts[(size_t)n * V3 + 3 * v + q] = s[0] * x + s[1] * y + s[2] * z + s[3];
      }
    }
  }
}

extern "C" void kernel_launch(void* const* d_in, const int* in_sizes, int n_in,
                              void* d_out, int out_size, void* d_ws, size_t ws_size,
                              hipStream_t stream) {
  const float* beta   = (const float*)d_in[0];
  const float* theta  = (const float*)d_in[1];
  const float* se     = (const float*)d_in[2];
  const float* deform = (const float*)d_in[3];
  const float* trans  = (const float*)d_in[4];
  const float* vt     = (const float*)d_in[5];
  const float* sd     = (const float*)d_in[6];
  const float* pd     = (const float*)d_in[7];
  const float* Jr     = (const float*)d_in[8];
  const float* wts    = (const float*)d_in[9];

  float* out    = (float*)d_out;
  float* verts  = out;
  float* joints = out + (size_t)N_ * V3;
  float* Rs     = joints + (size_t)N_ * 105;

  char* w = (char*)d_ws;
  unsigned short* pdT   = (unsigned short*)w;                    // 8,290,304 B
  unsigned short* pfA   = (unsigned short*)(w + 8290304);        //   360,448 B
  float* Jp    = (float*)(w + 8650752);                          //   215,040 B
  unsigned short* AwB   = (unsigned short*)(w + 8865792);        // 1,048,576 B
  float* JrT36 = (float*)(w + 9914368);                          //   560,016 B
  unsigned short* wtsB  = (unsigned short*)(w + 10474384);       //   501,760 B
  float* vtJr  = (float*)(w + 10976144);                         //       420 B
  float* sdJr  = (float*)(w + 10976564);                         //     8,400 B

  k_prep2<<<PREP_BLOCKS, 256, 0, stream>>>(Jr, wts, pd, sd, vt,
                                           JrT36, wtsB, pdT, vtJr, sdJr);
  k_jp<<<N_, 512, 0, stream>>>(deform, JrT36, vtJr, sdJr, beta, Jp);
  k_chain_rod<<<N_ / 4, 256, 0, stream>>>(theta, Jp, se, trans, beta, Rs, pfA, AwB);
  k_vposed_skin<<<dim3(49, 16), 256, 0, stream>>>(pfA, pdT, AwB, wtsB, vt, deform, verts);
  k_jreduce5<<<N_, 512, 0, stream>>>(verts, JrT36, joints);
}

// Round 9
// 226.017 us; speedup vs baseline: 1.2997x; 1.1329x over previous
//
#include <hip/hip_runtime.h>

#define N_   512
#define V_   3889
#define V3   11667      // V_*3
#define J_   35
#define NB_  20
#define PF_K 306        // 34*9
#define KP2  352        // K = [pf 306 | beta 20 | pad 26], 11 k-steps of 32
#define KS2  11
#define EP2  11776      // pdT rows
#define WROWS 3920      // wtsB rows (49*80)

typedef __attribute__((ext_vector_type(8))) short short8;
typedef __attribute__((ext_vector_type(4))) float f32x4;

__constant__ int c_parents[J_] = {0,0,1,2,3,4,5,6,7,8,9,6,11,12,13,6,15,16,17,18,
                                  16,20,21,22,23,16,25,26,27,28,29,30,16,1,1};

static __device__ __forceinline__ unsigned short f2bf(float x) {
  union { float f; unsigned int u; } v; v.f = x;
  unsigned int r = v.u + 0x7FFF + ((v.u >> 16) & 1);   // round-to-nearest-even
  return (unsigned short)(r >> 16);
}

// ===== prep A (pure layout, fine-grained): ==================================
//  A: JrT36[j][v] = Jr[v][j] (row 35 = 0)          547 blocks
//  B: wtsB[v][64] bf16 (j/v-pad zeroed)            245 blocks
//  C: pdT[e][KP2] bf16 = [pd | sd | 0] transposed  2024 blocks (1 octet/thread)
#define PA_JRT 547
#define PA_WTS 245
#define PA_PD  2024                     // 184 e-chunks x 11 oct4-groups
#define PA_BLOCKS (PA_JRT + PA_WTS + PA_PD)
__global__ __launch_bounds__(256) void k_prep_a(
    const float* __restrict__ Jr,  const float* __restrict__ wts,
    const float* __restrict__ pd,  const float* __restrict__ sd,
    float* __restrict__ JrT36, unsigned short* __restrict__ wtsB,
    unsigned short* __restrict__ pdT) {
  int b = blockIdx.x;
  int t = threadIdx.x;
  if (b < PA_JRT) {                      // ---- JrT36 ----
    int idx = b * 256 + t;
    if (idx >= 36 * V_) return;
    int j = idx / V_, v = idx % V_;
    JrT36[idx] = (j < J_) ? Jr[v * J_ + j] : 0.f;
  } else if (b < PA_JRT + PA_WTS) {      // ---- wtsB bf16 ----
    int bb = b - PA_JRT;
    int v   = bb * 16 + (t >> 4);
    int jk0 = (t & 15) * 4;
    unsigned short pk[4];
#pragma unroll
    for (int i = 0; i < 4; ++i) {
      int j = jk0 + i;
      float x = (v < V_ && j < J_) ? wts[(size_t)v * J_ + j] : 0.f;
      pk[i] = f2bf(x);
    }
    *(unsigned long long*)(wtsB + (size_t)v * 64 + jk0) = *(unsigned long long*)pk;
  } else {                               // ---- pdT bf16, one octet/thread ----
    int pp = b - (PA_JRT + PA_WTS);
    int ec = pp % 184, o4 = pp / 184;
    int e  = ec * 64 + (t & 63);
    int oc = o4 * 4 + (t >> 6);          // 0..43
    int k0 = oc * 8;
    bool ev = e < V3;
    union { unsigned short u[8]; short8 s; } pk;
#pragma unroll
    for (int ii = 0; ii < 8; ++ii) {
      int k = k0 + ii;
      float x = 0.f;
      if (ev && k < PF_K)            x = pd[(size_t)k * V3 + e];
      else if (ev && k < PF_K + NB_) x = sd[(size_t)(k - PF_K) * V3 + e];
      pk.u[ii] = f2bf(x);
    }
    *(short8*)(pdT + (size_t)e * KP2 + k0) = pk.s;
  }
}

// ===== jp_plus: blocks<512: JpRaw[n] = deform_n @ Jr ========================
//        blocks>=512 (84 = 21 dims x 4 v-chunks): atomicAdd vtsdJr[d][105]
#define JRJG 9
__global__ __launch_bounds__(512) void k_jp_plus(
    const float* __restrict__ deform, const float* __restrict__ JrT36,
    const float* __restrict__ vt,     const float* __restrict__ sd,
    float* __restrict__ JpRaw, float* __restrict__ vtsdJr) {
  __shared__ float part[8][27];
  int b = blockIdx.x;
  int t = threadIdx.x;
  int lane = t & 63, w = t >> 6;
  int jg = w & 3, vh = w >> 2;
  int j0 = jg * JRJG;

  const float* s0;
  int iv0, ivn;
  if (b < N_) {
    s0 = deform + (size_t)b * V3;
    iv0 = vh * 31; ivn = vh ? 30 : 31;           // 61 chunks of 64 v
  } else {
    int bb = b - N_;
    int d = bb >> 2, ch = bb & 3;
    s0 = (d == 0) ? vt : sd + (size_t)(d - 1) * V3;
    int c0 = ch * 15, cn = (ch == 3) ? 16 : 15;  // 15+15+15+16 = 61
    int h = cn >> 1;
    iv0 = c0 + (vh ? h : 0);
    ivn = vh ? (cn - h) : h;
  }

  float acc[JRJG][3];
#pragma unroll
  for (int jj = 0; jj < JRJG; ++jj)
#pragma unroll
    for (int cc = 0; cc < 3; ++cc) acc[jj][cc] = 0.f;

#pragma unroll 2
  for (int i = 0; i < ivn; ++i) {
    int v = (iv0 + i) * 64 + lane;
    bool ok = v < V_;
    float jr[JRJG];
#pragma unroll
    for (int jj = 0; jj < JRJG; ++jj)
      jr[jj] = ok ? JrT36[(size_t)(j0 + jj) * V_ + v] : 0.f;
    float sx = ok ? s0[3 * v + 0] : 0.f;
    float sy = ok ? s0[3 * v + 1] : 0.f;
    float sz = ok ? s0[3 * v + 2] : 0.f;
#pragma unroll
    for (int jj = 0; jj < JRJG; ++jj) {
      acc[jj][0] += jr[jj] * sx;
      acc[jj][1] += jr[jj] * sy;
      acc[jj][2] += jr[jj] * sz;
    }
  }

#pragma unroll
  for (int jj = 0; jj < JRJG; ++jj)
#pragma unroll
    for (int cc = 0; cc < 3; ++cc) {
      float v = acc[jj][cc];
#pragma unroll
      for (int off = 32; off > 0; off >>= 1)
        v += __shfl_down(v, off, 64);
      if (lane == 0) part[w][jj * 3 + cc] = v;
    }
  __syncthreads();

  if (t < 108) {
    int g = t / 27, idx = t % 27;
    int j = g * JRJG + idx / 3;
    if (j < J_) {
      float val = part[g][idx] + part[g + 4][idx];
      if (b < N_) JpRaw[b * 105 + j * 3 + idx % 3] = val;
      else atomicAdd(&vtsdJr[((b - N_) >> 2) * 105 + j * 3 + idx % 3], val);
    }
  }
}

// ===== jreduce (joints): dst[n,jc] = sum_v src[n,3v+c]*JrT36[j,v] ===========
__global__ __launch_bounds__(512) void k_jreduce5(
    const float* __restrict__ src, const float* __restrict__ JrT36,
    float* __restrict__ dst) {
  __shared__ float part[8][27];
  int t = threadIdx.x;
  int lane = t & 63;
  int w = t >> 6;
  int jg = w & 3, vh = w >> 2;
  int n = blockIdx.x;
  int j0 = jg * JRJG;
  const float* s0 = src + (size_t)n * V3;

  float acc[JRJG][3];
#pragma unroll
  for (int jj = 0; jj < JRJG; ++jj)
#pragma unroll
    for (int cc = 0; cc < 3; ++cc) acc[jj][cc] = 0.f;

  int iv0 = vh * 31;
  int ivn = vh ? 30 : 31;
#pragma unroll 2
  for (int i = 0; i < ivn; ++i) {
    int v = (iv0 + i) * 64 + lane;
    bool ok = v < V_;
    float jr[JRJG];
#pragma unroll
    for (int jj = 0; jj < JRJG; ++jj)
      jr[jj] = ok ? JrT36[(size_t)(j0 + jj) * V_ + v] : 0.f;
    float sx = ok ? s0[3 * v + 0] : 0.f;
    float sy = ok ? s0[3 * v + 1] : 0.f;
    float sz = ok ? s0[3 * v + 2] : 0.f;
#pragma unroll
    for (int jj = 0; jj < JRJG; ++jj) {
      acc[jj][0] += jr[jj] * sx;
      acc[jj][1] += jr[jj] * sy;
      acc[jj][2] += jr[jj] * sz;
    }
  }

#pragma unroll
  for (int jj = 0; jj < JRJG; ++jj)
#pragma unroll
    for (int cc = 0; cc < 3; ++cc) {
      float v = acc[jj][cc];
#pragma unroll
      for (int off = 32; off > 0; off >>= 1)
        v += __shfl_down(v, off, 64);
      if (lane == 0) part[w][jj * 3 + cc] = v;
    }
  __syncthreads();

  if (t < 108) {
    int g = t / 27, idx = t % 27;
    int j = g * JRJG + idx / 3;
    if (j < J_)
      dst[n * 105 + j * 3 + idx % 3] = part[g][idx] + part[g + 4][idx];
  }
}

// ===== Rodrigues + Jp finalize (LDS) + chain -> Rs, pfA, AwB ================
__global__ __launch_bounds__(256) void k_chain_rod(
    const float* __restrict__ theta, const float* __restrict__ JpRaw,
    const float* __restrict__ vtsdJr,
    const float* __restrict__ se,    const float* __restrict__ trans,
    const float* __restrict__ beta,
    float* __restrict__ Rs_out, unsigned short* __restrict__ pfA,
    unsigned short* __restrict__ AwB) {
  __shared__ float loc[4][J_][12];
  __shared__ float res[4][J_][12];
  __shared__ float Jp_s[4][J_][3];
  int t = threadIdx.x;
  int w = t >> 6, l = t & 63;
  int n = blockIdx.x * 4 + w;
  int mt = n >> 4, m = n & 15;

  float r[9];
  if (l < J_) {
    int j = l;
    const float* th = theta + n * (J_ * 3) + j * 3;
    float t0 = th[0], t1 = th[1], t2 = th[2];
    float angle = sqrtf(t0 * t0 + t1 * t1 + t2 * t2 + 1e-8f);
    float inv = 1.0f / angle;
    float r0 = t0 * inv, r1 = t1 * inv, r2 = t2 * inv;
    float s, c;
    sincosf(angle, &s, &c);
    float omc = 1.0f - c;
    r[0] = c + omc * r0 * r0;      r[1] = omc * r0 * r1 - s * r2;  r[2] = omc * r0 * r2 + s * r1;
    r[3] = omc * r1 * r0 + s * r2; r[4] = c + omc * r1 * r1;       r[5] = omc * r1 * r2 - s * r0;
    r[6] = omc * r2 * r0 - s * r1; r[7] = omc * r2 * r1 + s * r0;  r[8] = c + omc * r2 * r2;

    float* ro = Rs_out + (size_t)n * (J_ * 9) + j * 9;
#pragma unroll
    for (int k = 0; k < 9; ++k) ro[k] = r[k];
    if (j > 0) {
#pragma unroll
      for (int kk = 0; kk < 9; ++kk) {
        int k = (j - 1) * 9 + kk;
        float v = r[kk] - ((kk == 0 || kk == 4 || kk == 8) ? 1.0f : 0.0f);
        size_t idx = ((((size_t)mt * KS2 + (k >> 5)) * 4 + ((k >> 3) & 3)) * 16 + m) * 8 + (k & 7);
        pfA[idx] = f2bf(v);
      }
    }
    // Jp finalize: Jp = JpRaw + vtJr + beta @ sdJr
    const float* bn = beta + n * NB_;
#pragma unroll
    for (int cc = 0; cc < 3; ++cc) {
      int jc = j * 3 + cc;
      float val = JpRaw[n * 105 + jc] + vtsdJr[jc];
#pragma unroll
      for (int bb = 0; bb < NB_; ++bb)
        val += bn[bb] * vtsdJr[(1 + bb) * 105 + jc];
      Jp_s[w][j][cc] = val;
    }
  } else {
    // lanes 35..63: AwB j-pad zero + pfA beta rows + pfA k-pad zeros
    unsigned short* An = AwB + (size_t)n * 16 * 64 + l;
#pragma unroll
    for (int d = 0; d < 16; ++d) An[d * 64] = 0;
    if (l < 55) {                    // beta -> k = 306 + (l-35)
      int k = PF_K + (l - 35);
      size_t idx = ((((size_t)mt * KS2 + (k >> 5)) * 4 + ((k >> 3) & 3)) * 16 + m) * 8 + (k & 7);
      pfA[idx] = f2bf(beta[n * NB_ + (l - 35)]);
    } else {                         // zeros k = 326..351
      for (int k = PF_K + NB_ + (l - 55); k < KP2; k += 9) {
        size_t idx = ((((size_t)mt * KS2 + (k >> 5)) * 4 + ((k >> 3) & 3)) * 16 + m) * 8 + (k & 7);
        pfA[idx] = 0;
      }
    }
  }
  __syncthreads();

  if (l < J_) {
    int j = l;
    if (j == 0) {
#pragma unroll
      for (int rr = 0; rr < 3; ++rr) {
        loc[w][0][rr * 4 + 0] = r[rr * 3 + 0];
        loc[w][0][rr * 4 + 1] = r[rr * 3 + 1];
        loc[w][0][rr * 4 + 2] = r[rr * 3 + 2];
        loc[w][0][rr * 4 + 3] = Jp_s[w][0][rr];
      }
#pragma unroll
      for (int k = 0; k < 12; ++k) res[w][0][k] = loc[w][0][k];
    } else {
      int p = c_parents[j];
      float si[3], sp[3], jh[3];
#pragma unroll
      for (int cidx = 0; cidx < 3; ++cidx) {
        si[cidx] = se[n * 105 + j * 3 + cidx];
        sp[cidx] = se[n * 105 + p * 3 + cidx];
        jh[cidx] = Jp_s[w][j][cidx] - Jp_s[w][p][cidx];
      }
#pragma unroll
      for (int rr = 0; rr < 3; ++rr) {
        float invp = 1.0f / sp[rr];
        loc[w][j][rr * 4 + 0] = r[rr * 3 + 0] * si[0] * invp;
        loc[w][j][rr * 4 + 1] = r[rr * 3 + 1] * si[1] * invp;
        loc[w][j][rr * 4 + 2] = r[rr * 3 + 2] * si[2] * invp;
        loc[w][j][rr * 4 + 3] = jh[rr];
      }
    }
  }
  __syncthreads();

  for (int i = 1; i < J_; ++i) {
    if (l < 12) {
      int p = c_parents[i];
      int rr = l >> 2, cc = l & 3;
      float acc = (cc == 3) ? res[w][p][rr * 4 + 3] : 0.f;
#pragma unroll
      for (int k = 0; k < 3; ++k)
        acc += res[w][p][rr * 4 + k] * loc[w][i][k * 4 + cc];
      res[w][i][l] = acc;
    }
    __syncthreads();
  }

  if (l < J_) {
    int j = l;
    float jx = Jp_s[w][j][0];
    float jy = Jp_s[w][j][1];
    float jz = Jp_s[w][j][2];
    unsigned short* An = AwB + (size_t)n * 16 * 64 + j;
#pragma unroll
    for (int rr = 0; rr < 3; ++rr) {
      float a0 = res[w][j][rr * 4 + 0];
      float a1 = res[w][j][rr * 4 + 1];
      float a2 = res[w][j][rr * 4 + 2];
      float a3 = res[w][j][rr * 4 + 3] - (a0 * jx + a1 * jy + a2 * jz)
               + trans[n * 3 + rr];
      An[(rr * 4 + 0) * 64] = f2bf(a0);
      An[(rr * 4 + 1) * 64] = f2bf(a1);
      An[(rr * 4 + 2) * 64] = f2bf(a2);
      An[(rr * 4 + 3) * 64] = f2bf(a3);
    }
  }
}

// ===== fused: v_posed (MFMA K=352) + LDS + skin (MFMA) -> verts =============
// grid(49, 8): block = 64 n x 240 e (256 computed).
#define LSTR 242
__global__ __launch_bounds__(256) void k_vposed_skin(
    const unsigned short* __restrict__ pfA, const unsigned short* __restrict__ pdT,
    const unsigned short* __restrict__ AwB, const unsigned short* __restrict__ wtsB,
    const float* __restrict__ vt, const float* __restrict__ deform,
    float* __restrict__ verts) {
  __shared__ float lds[64 * LSTR];
  int t = threadIdx.x;
  int wv = t >> 6, lane = t & 63;
  int q = lane >> 4, col = lane & 15;
  int bx = blockIdx.x, by = blockIdx.y;
  int mtg0 = by * 4;
  int ebase = bx * 240 + wv * 64;

  const short8* Ap = (const short8*)pfA;
  const short8* Bp = (const short8*)pdT;

  // ---- phase 1: [pf|beta] @ [pd;sd]  (K=352, M=64) ----
  f32x4 acc[4][4];
#pragma unroll
  for (int mt = 0; mt < 4; ++mt)
#pragma unroll
    for (int et = 0; et < 4; ++et) acc[mt][et] = (f32x4){0.f, 0.f, 0.f, 0.f};

#pragma unroll
  for (int ks = 0; ks < KS2; ++ks) {
    short8 a[4];
#pragma unroll
    for (int mt = 0; mt < 4; ++mt)
      a[mt] = Ap[(((mtg0 + mt) * KS2 + ks) * 4 + q) * 16 + col];
    short8 b[4];
#pragma unroll
    for (int et = 0; et < 4; ++et)
      b[et] = Bp[(size_t)(ebase + et * 16 + col) * (KP2 / 8) + ks * 4 + q];
#pragma unroll
    for (int mt = 0; mt < 4; ++mt)
#pragma unroll
      for (int et = 0; et < 4; ++et)
        acc[mt][et] = __builtin_amdgcn_mfma_f32_16x16x32_bf16(a[mt], b[et], acc[mt][et], 0, 0, 0);
  }

  // ---- phase 2: += vt + deform, stage v_posed tile in LDS ----
#pragma unroll
  for (int et = 0; et < 4; ++et) {
    int e_loc = wv * 64 + et * 16 + col;
    int e = bx * 240 + e_loc;
    bool ev = (e < V3) && (e_loc < 240);
    float vte = ev ? vt[e] : 0.f;
#pragma unroll
    for (int mt = 0; mt < 4; ++mt) {
#pragma unroll
      for (int r = 0; r < 4; ++r) {
        int n_loc = mt * 16 + q * 4 + r;
        if (ev) {
          int n = by * 64 + n_loc;
          float df = deform[(size_t)n * V3 + e];
          lds[n_loc * LSTR + e_loc] = acc[mt][et][r] + vte + df;
        }
      }
    }
  }
  __syncthreads();

  // ---- phase 3: skin via MFMA, write final verts ----
  short8 bw0[5], bw1[5];
#pragma unroll
  for (int v5 = 0; v5 < 5; ++v5) {
    int v = bx * 80 + v5 * 16 + col;
    const short8* Wp = (const short8*)(wtsB + (size_t)v * 64);
    bw0[v5] = Wp[q];
    bw1[v5] = Wp[4 + q];
  }
#pragma unroll 2
  for (int ni = 0; ni < 16; ++ni) {
    int n_loc = wv * 16 + ni;
    int n = by * 64 + n_loc;
    const short8* Aq = (const short8*)(AwB + ((size_t)n * 16 + col) * 64);
    short8 a0 = Aq[q];
    short8 a1 = Aq[4 + q];
#pragma unroll
    for (int v5 = 0; v5 < 5; ++v5) {
      f32x4 s = (f32x4){0.f, 0.f, 0.f, 0.f};
      s = __builtin_amdgcn_mfma_f32_16x16x32_bf16(a0, bw0[v5], s, 0, 0, 0);
      s = __builtin_amdgcn_mfma_f32_16x16x32_bf16(a1, bw1[v5], s, 0, 0, 0);
      int vl = v5 * 16 + col;
      int v = bx * 80 + vl;
      if (v < V_ && q < 3) {
        float x = lds[n_loc * LSTR + 3 * vl + 0];
        float y = lds[n_loc * LSTR + 3 * vl + 1];
        float z = lds[n_loc * LSTR + 3 * vl + 2];
        verts[(size_t)n * V3 + 3 * v + q] = s[0] * x + s[1] * y + s[2] * z + s[3];
      }
    }
  }
}

extern "C" void kernel_launch(void* const* d_in, const int* in_sizes, int n_in,
                              void* d_out, int out_size, void* d_ws, size_t ws_size,
                              hipStream_t stream) {
  const float* beta   = (const float*)d_in[0];
  const float* theta  = (const float*)d_in[1];
  const float* se     = (const float*)d_in[2];
  const float* deform = (const float*)d_in[3];
  const float* trans  = (const float*)d_in[4];
  const float* vt     = (const float*)d_in[5];
  const float* sd     = (const float*)d_in[6];
  const float* pd     = (const float*)d_in[7];
  const float* Jr     = (const float*)d_in[8];
  const float* wts    = (const float*)d_in[9];

  float* out    = (float*)d_out;
  float* verts  = out;
  float* joints = out + (size_t)N_ * V3;
  float* Rs     = joints + (size_t)N_ * 105;

  char* w = (char*)d_ws;
  unsigned short* pdT    = (unsigned short*)w;                   // 8,290,304 B
  unsigned short* pfA    = (unsigned short*)(w + 8290304);       //   360,448 B
  float* JpRaw  = (float*)(w + 8650752);                         //   215,040 B
  unsigned short* AwB    = (unsigned short*)(w + 8865792);       // 1,048,576 B
  float* JrT36  = (float*)(w + 9914368);                         //   560,016 B
  unsigned short* wtsB   = (unsigned short*)(w + 10474384);      //   501,760 B
  float* vtsdJr = (float*)(w + 10976144);                        //     8,820 B

  hipMemsetAsync(vtsdJr, 0, 21 * 105 * sizeof(float), stream);
  k_prep_a<<<PA_BLOCKS, 256, 0, stream>>>(Jr, wts, pd, sd, JrT36, wtsB, pdT);
  k_jp_plus<<<N_ + 84, 512, 0, stream>>>(deform, JrT36, vt, sd, JpRaw, vtsdJr);
  k_chain_rod<<<N_ / 4, 256, 0, stream>>>(theta, JpRaw, vtsdJr, se, trans, beta,
                                          Rs, pfA, AwB);
  k_vposed_skin<<<dim3(49, 8), 256, 0, stream>>>(pfA, pdT, AwB, wtsB, vt, deform, verts);
  k_jreduce5<<<N_, 512, 0, stream>>>(verts, JrT36, joints);
}